// Round 9
// baseline (373.675 us; speedup 1.0000x reference)
//
#include <hip/hip_runtime.h>
#include <hip/hip_fp16.h>
#include <math.h>

#define Q    4096
#define NN   16384
#define DD   256
#define KSEL 33
#define CANDW 256  // per-ROW candidate cap
#define OSTR 264   // epilogue LDS row stride bytes: 256 B data + 8 B pad
#define TM_BYTES (128 * Q * 2)                 // tilemax[tileN][row] u16 keys
#define WS_NORMS ((size_t)(Q + NN) * 4)
#define WS_FULL  (WS_NORMS + TM_BYTES)

// R9 MEASUREMENT ROUND: R8 code unchanged except rowsel processes 2 rows per
// wave sequentially (grid 512). This pushes the rowsel dispatch (~230 us if
// rowsel_1x ~117) above the top-5 display cutoff (~160 us, all harness fills)
// so its FETCH/WRITE/VALU/Occupancy counters become visible for the first
// time. Model vs measurement gap is 3-4x; the counters arbitrate.

typedef __attribute__((ext_vector_type(8))) _Float16 half8;
typedef __attribute__((ext_vector_type(4))) float    floatx4;

__device__ __forceinline__ float h2f(unsigned short u) {
    union { unsigned short s; _Float16 h; } c; c.s = u;
    return (float)c.h;
}
// f32 -> f16 raw bits, guaranteed FINITE pattern (exp field != 0x1F)
__device__ __forceinline__ unsigned short f2h_finite(float v) {
    v = fminf(fmaxf(v, -65504.0f), 65504.0f);       // IEEE fmax/fmin: NaN -> -65504
    union { _Float16 h; unsigned short s; } c; c.h = (_Float16)v;
    unsigned short u = c.s;
    if ((u & 0x7C00u) == 0x7C00u) u = (u & 0x8000u) ? 0xFBFFu : 0x7BFFu;
    return u;
}
__device__ __forceinline__ unsigned int patch16(unsigned int u) {
    if ((u & 0x7C00u) == 0x7C00u) u = (u & 0x8000u) ? 0xFBFFu : 0x7BFFu;
    return u;
}
// keys are SORTABLE u16: key = f16bits(nd2) ^ 0xFFFF, nd2 = -d2 <= +0.
__device__ __forceinline__ unsigned short keyd2_to_out(unsigned int k) {
    const float nd2 = h2f((unsigned short)patch16(k ^ 0xFFFFu));   // = -d2 (finite, <= 0)
    return f2h_finite(-sqrtf(fmaxf(-nd2, 0.0f)));
}
// async 16B global -> LDS (m97). Dest = wave-uniform base + lane*16 [m104].
__device__ __forceinline__ void gload_lds16(const unsigned short* g, char* l) {
    __builtin_amdgcn_global_load_lds(
        (const __attribute__((address_space(1))) void*)g,
        (__attribute__((address_space(3))) void*)l, 16, 0, 0);
}

// ---------------------------------------------------------------- row norms -> ws
__global__ __launch_bounds__(256) void norms_kernel(const unsigned short* __restrict__ x,
                                                    const unsigned short* __restrict__ xn,
                                                    float* __restrict__ ws) {
    const int t = threadIdx.x;
    const int g = blockIdx.x * 64 + (t >> 2);
    const int sub = t & 3;
    const unsigned short* src = (g < Q) ? (x + (size_t)g * DD)
                                        : (xn + (size_t)(g - Q) * DD);
    float s = 0.f;
#pragma unroll
    for (int it = 0; it < 8; ++it) {
        const uint4 v = *(const uint4*)(src + (it * 4 + sub) * 8);
        const unsigned int* w = (const unsigned int*)&v;
#pragma unroll
        for (int q = 0; q < 4; ++q) {
            const float a = h2f(w[q] & 0xFFFF), b = h2f(w[q] >> 16);
            s = fmaf(a, a, s); s = fmaf(b, b, s);
        }
    }
    s += __shfl_xor(s, 1);
    s += __shfl_xor(s, 2);
    if (sub == 0) ws[g] = s;
}

// ---------------------------------------------------------------- sim GEMM (MFMA f16)
// v16 (R3 best, ~71 us warm via R7 amplification): XCD-chunked swizzle +
// single-buffer pipeline (BK=64) + pre-keyed u16 epilogue + fused tilemax.
template <bool WS, bool TM>
__global__ __launch_bounds__(256) void gemm_sim_kernel(const unsigned short* __restrict__ A,
                                                       const unsigned short* __restrict__ B,
                                                       const float* __restrict__ ws,
                                                       unsigned short* __restrict__ tmax,
                                                       unsigned short* __restrict__ out) {
    __shared__ char  lds[128 * OSTR];
    __shared__ float s_x2[128];
    __shared__ float s_y2[128];
    char* ldsA = lds;              // [kk 2][row 128][64 B]  = 16 KB
    char* ldsB = lds + 16384;      // [kk 2][row 128][64 B]  = 16 KB

    const int t    = threadIdx.x;
    const int bid  = blockIdx.x + blockIdx.y * (NN / 128);
    const int xcd  = bid & 7;
    const int qb   = bid >> 3;                   // 0..511
    const int n0   = ((xcd << 4) | (qb & 15)) * 128;
    const int m0   = (qb >> 4) * 128;
    const int wave = t >> 6;
    const int lane = t & 63;
    const int wm   = (wave & 1) << 6;
    const int wn   = (wave >> 1) << 6;
    const int l15  = lane & 15;
    const int quad = lane >> 4;
    const int r0   = t >> 2;
    const int qq   = t & 3;

    if (WS) {
        if (t < 128) s_x2[t] = ws[m0 + t];
        else         s_y2[t - 128] = ws[Q + n0 + (t - 128)];
    }

    floatx4 acc[4][4];
#pragma unroll
    for (int i = 0; i < 4; ++i)
#pragma unroll
        for (int j = 0; j < 4; ++j) {
            acc[i][j][0] = 0.f; acc[i][j][1] = 0.f; acc[i][j][2] = 0.f; acc[i][j][3] = 0.f;
        }
    float pa[2] = {0.f, 0.f}, pb[2] = {0.f, 0.f};

    if (WS) {
#pragma unroll
        for (int j = 0; j < 4; ++j) {
            const int row = ((j & 1) << 6) + r0;
            const int kd  = ((j >> 1) << 5) + (qq << 3);
            gload_lds16(A + (size_t)(m0 + row) * DD + kd, ldsA + j * 4096 + t * 16);
            gload_lds16(B + (size_t)(n0 + row) * DD + kd, ldsB + j * 4096 + t * 16);
        }
#pragma unroll
        for (int kt = 0; kt < 4; ++kt) {
            __syncthreads();                 // b1: all loads for tile kt landed (vmcnt drain)
            half8 af[2][4], bg[2][4];
#pragma unroll
            for (int kk = 0; kk < 2; ++kk)
#pragma unroll
                for (int s = 0; s < 4; ++s) {
                    af[kk][s] = *(const half8*)(ldsA + (kk << 13) + (wm + s * 16 + l15) * 64 + quad * 16);
                    bg[kk][s] = *(const half8*)(ldsB + (kk << 13) + (wn + s * 16 + l15) * 64 + quad * 16);
                }
            __syncthreads();                 // b2: all waves' frags in regs (lgkm drained)
            if (kt < 3) {                    // issue NEXT tile into same buffer; MFMAs hide latency
                const int kn = (kt + 1) * 64;
#pragma unroll
                for (int j = 0; j < 4; ++j) {
                    const int row = ((j & 1) << 6) + r0;
                    const int kd  = kn + ((j >> 1) << 5) + (qq << 3);
                    gload_lds16(A + (size_t)(m0 + row) * DD + kd, ldsA + j * 4096 + t * 16);
                    gload_lds16(B + (size_t)(n0 + row) * DD + kd, ldsB + j * 4096 + t * 16);
                }
            }
#pragma unroll
            for (int kk = 0; kk < 2; ++kk)
#pragma unroll
                for (int si = 0; si < 4; ++si)
#pragma unroll
                    for (int sj = 0; sj < 4; ++sj)
                        acc[si][sj] = __builtin_amdgcn_mfma_f32_16x16x32_f16(af[kk][si], bg[kk][sj], acc[si][sj], 0, 0, 0);
        }
    } else {
        for (int k0 = 0; k0 < DD; k0 += 64) {
            float4 ar[4], br[4];
#pragma unroll
            for (int j = 0; j < 4; ++j) {
                const int r  = r0 + ((j & 1) << 6);
                const int kd = k0 + ((j >> 1) << 5);
                ar[j] = *(const float4*)(A + (size_t)(m0 + r) * DD + kd + qq * 8);
                br[j] = *(const float4*)(B + (size_t)(n0 + r) * DD + kd + qq * 8);
                const unsigned short* ua = (const unsigned short*)&ar[j];
                const unsigned short* ub = (const unsigned short*)&br[j];
#pragma unroll
                for (int e = 0; e < 8; ++e) {
                    const float fa = h2f(ua[e]); pa[j & 1] = fmaf(fa, fa, pa[j & 1]);
                    const float fb = h2f(ub[e]); pb[j & 1] = fmaf(fb, fb, pb[j & 1]);
                }
            }
            __syncthreads();
#pragma unroll
            for (int j = 0; j < 4; ++j) {
                const int r = r0 + ((j & 1) << 6);
                *(float4*)(ldsA + ((j >> 1) << 13) + r * 64 + qq * 16) = ar[j];
                *(float4*)(ldsB + ((j >> 1) << 13) + r * 64 + qq * 16) = br[j];
            }
            __syncthreads();
#pragma unroll
            for (int kk = 0; kk < 2; ++kk) {
                half8 af[4], bg[4];
#pragma unroll
                for (int s = 0; s < 4; ++s) {
                    af[s] = *(const half8*)(ldsA + (kk << 13) + (wm + s * 16 + l15) * 64 + quad * 16);
                    bg[s] = *(const half8*)(ldsB + (kk << 13) + (wn + s * 16 + l15) * 64 + quad * 16);
                }
#pragma unroll
                for (int si = 0; si < 4; ++si)
#pragma unroll
                    for (int sj = 0; sj < 4; ++sj)
                        acc[si][sj] = __builtin_amdgcn_mfma_f32_16x16x32_f16(af[si], bg[sj], acc[si][sj], 0, 0, 0);
            }
            __syncthreads();                 // protect LDS before next iteration's writes
        }
#pragma unroll
        for (int j = 0; j < 2; ++j) {
            pa[j] += __shfl_xor(pa[j], 1); pa[j] += __shfl_xor(pa[j], 2);
            pb[j] += __shfl_xor(pb[j], 1); pb[j] += __shfl_xor(pb[j], 2);
        }
        if (qq == 0) {
            s_x2[r0] = pa[0]; s_x2[64 + r0] = pa[1];
            s_y2[r0] = pb[0]; s_y2[64 + r0] = pb[1];
        }
        __syncthreads();
    }

    // ---- epilogue: nd2 = min(2*acc - x2 - y2, 0); store key = bits(f16(nd2)) ^ 0xFFFF
    {
        float ny[4];
#pragma unroll
        for (int sj = 0; sj < 4; ++sj) ny[sj] = -s_y2[wn + sj * 16 + l15];
#pragma unroll
        for (int si = 0; si < 4; ++si) {
#pragma unroll
            for (int r = 0; r < 4; ++r) {
                const int lrow = wm + si * 16 + quad * 4 + r;
                const float nx = -s_x2[lrow];
#pragma unroll
                for (int sj = 0; sj < 4; ++sj) {
                    const float nd2 = fminf(fmaf(2.0f, acc[si][sj][r], nx + ny[sj]), 0.0f);
                    union { _Float16 h; unsigned short s; } c; c.h = (_Float16)nd2;
                    *(unsigned short*)(lds + lrow * OSTR + (wn + sj * 16 + l15) * 2) =
                        (unsigned short)(c.s ^ 0xFFFFu);
                }
            }
        }
    }
    __syncthreads();

    // ---- key-store pass with fused tilemax (16-lane shfl reduce per row slice)
#pragma unroll
    for (int p = 0; p < 8; ++p) {
        const int idx = p * 256 + t;
        const int r = idx >> 4, c = idx & 15;
        const uint4 v = *(const uint4*)(lds + r * OSTR + c * 16);
        *(uint4*)(out + (size_t)(m0 + r) * NN + n0 + c * 8) = v;
        if (TM) {
            const unsigned int* w = (const unsigned int*)&v;
            unsigned int mk = 0;
#pragma unroll
            for (int q = 0; q < 4; ++q) {
                const unsigned int a = w[q] & 0xFFFFu, b = w[q] >> 16;
                const unsigned int m = a > b ? a : b;
                mk = m > mk ? m : mk;
            }
#pragma unroll
            for (int off = 1; off < 16; off <<= 1) {
                const unsigned int o = (unsigned int)__shfl_xor((int)mk, off);
                mk = o > mk ? o : mk;
            }
            if (c == 0) tmax[(size_t)(n0 >> 7) * Q + m0 + r] = (unsigned short)mk;
        }
    }
}

// ---------------------------------------------------------------- row select v7: wave-per-row x2 (MEASUREMENT)
// Identical per-row logic to v6 (R8); each wave handles TWO rows sequentially
// so the dispatch (~2x longer) rises above the top-5 cutoff and exposes its
// counters. Grid Q/8 = 512 blocks.
__global__ __launch_bounds__(256) void rowsel_kernel(unsigned short* __restrict__ out,
                                                     const unsigned short* __restrict__ tmax) {
    const int t = threadIdx.x;
    const int lane = t & 63;
    const int wave = t >> 6;

    __shared__ unsigned short s_tm[4][128];
    __shared__ unsigned int   s_cand[4][CANDW];   // (key<<16) | col

    for (int rr = 0; rr < 2; ++rr) {
        const int row = blockIdx.x * 8 + rr * 4 + wave;
        unsigned short* rowp = out + (size_t)row * NN;

        // tilemax: 2 per lane
        const unsigned int ka = tmax[(size_t)(2 * lane) * Q + row];
        const unsigned int kb = tmax[(size_t)(2 * lane + 1) * Q + row];
        s_tm[wave][2 * lane]     = (unsigned short)ka;
        s_tm[wave][2 * lane + 1] = (unsigned short)kb;

        // taulb bisection (wave-local ballots)
        unsigned int taulb = 0;
#pragma unroll
        for (int b = 15; b >= 0; --b) {
            const unsigned int tc = taulb | (1u << b);
            const int c = (int)__popcll(__ballot(ka >= tc)) + (int)__popcll(__ballot(kb >= tc));
            if (c >= KSEL) taulb = tc;       // wave-uniform
        }
        asm volatile("s_waitcnt lgkmcnt(0)" ::: "memory");   // s_tm visible (same wave)

        // pruned gather: 4 passes, pass i covers half-ranges i*64+lane
        int wbase = 0;
#pragma unroll
        for (int pass = 0; pass < 4; ++pass) {
            const int half  = pass * 64 + lane;
            const int cbase = half * 64;
            const bool act  = s_tm[wave][half >> 1] >= taulb;
            if (__ballot(act)) {
                uint4 d[8];
                int cge = 0;
                if (act) {
                    const uint4* tp = (const uint4*)(rowp + cbase);
#pragma unroll
                    for (int j = 0; j < 8; ++j) d[j] = tp[j];
#pragma unroll
                    for (int j = 0; j < 8; ++j) {
                        const unsigned int* w = (const unsigned int*)&d[j];
#pragma unroll
                        for (int q = 0; q < 4; ++q)
                            cge += (int)((w[q] & 0xFFFFu) >= taulb) + (int)((w[q] >> 16) >= taulb);
                    }
                }
                int p = cge;
#pragma unroll
                for (int off = 1; off < 64; off <<= 1) {
                    const int v = __shfl_up(p, off);
                    if (lane >= off) p += v;
                }
                int slot = wbase + p - cge;
                if (cge) {
#pragma unroll
                    for (int j = 0; j < 8; ++j) {
                        const unsigned int* w = (const unsigned int*)&d[j];
#pragma unroll
                        for (int q = 0; q < 4; ++q) {
#pragma unroll
                            for (int hh = 0; hh < 2; ++hh) {
                                const unsigned int k = hh ? (w[q] >> 16) : (w[q] & 0xFFFFu);
                                if (k >= taulb) {
                                    if (slot < CANDW)
                                        s_cand[wave][slot] = (k << 16) | (unsigned int)(cbase + j * 8 + q * 2 + hh);
                                    ++slot;
                                }
                            }
                        }
                    }
                }
                wbase += __shfl(p, 63);
                if (wbase > CANDW) wbase = CANDW;
            }
        }
        const int M = wbase;                  // wave-uniform candidate count

        asm volatile("s_waitcnt lgkmcnt(0)" ::: "memory");   // bank visible (same wave)
        unsigned int e[4]; bool val[4];
#pragma unroll
        for (int s = 0; s < 4; ++s) {
            const int i = lane + 64 * s;
            val[s] = (i < M);
            e[s] = val[s] ? s_cand[wave][i] : 0u;
        }

        // issue the row fill NOW; acks hide under the bisect below.
        const uint4 fv = {0xFBFFFBFFu, 0xFBFFFBFFu, 0xFBFFFBFFu, 0xFBFFFBFFu};
        uint4* wp4 = (uint4*)rowp;
#pragma unroll
        for (int j = 0; j < 32; ++j) wp4[j * 64 + lane] = fv;

        // exact T bisection over candidates (wave-local)
        unsigned int T = 0;
#pragma unroll
        for (int b = 15; b >= 0; --b) {
            const unsigned int tc = T | (1u << b);
            int c = 0;
#pragma unroll
            for (int s = 0; s < 4; ++s)
                c += (int)__popcll(__ballot(val[s] && (e[s] >> 16) >= tc));
            if (c >= KSEL) T = tc;
        }
        int cgt = 0;
        bool sel[4];
#pragma unroll
        for (int s = 0; s < 4; ++s) {
            sel[s] = val[s] && (e[s] >> 16) > T;
            cgt += (int)__popcll(__ballot(sel[s]));
        }
        int tneed = KSEL - cgt;
        if (tneed < 0) tneed = 0;

        asm volatile("s_waitcnt vmcnt(0)" ::: "memory");     // fill completed

        // scatter all key > T
#pragma unroll
        for (int s = 0; s < 4; ++s)
            if (sel[s]) rowp[e[s] & 0xFFFFu] = keyd2_to_out(e[s] >> 16);

        // append tneed lowest-col ties (key == T) via iterative butterfly-min
        const unsigned short tval = keyd2_to_out(T);
        bool taken[4] = {false, false, false, false};
        for (int k = 0; k < tneed; ++k) {
            int m = 0x7fffffff;
#pragma unroll
            for (int s = 0; s < 4; ++s)
                if (val[s] && !taken[s] && (e[s] >> 16) == T) {
                    const int g = (int)(e[s] & 0xFFFFu);
                    if (g < m) m = g;
                }
#pragma unroll
            for (int off = 1; off < 64; off <<= 1) {
                const int o = __shfl_xor(m, off);
                if (o < m) m = o;
            }
            if (m == 0x7fffffff) break;
#pragma unroll
            for (int s = 0; s < 4; ++s)
                if (val[s] && !taken[s] && (e[s] >> 16) == T && (int)(e[s] & 0xFFFFu) == m) {
                    taken[s] = true;
                    rowp[m] = tval;
                }
        }
        // wave-internal LDS reuse across rr is safe: ds ops from one wave
        // complete in issue order (reads of s_cand precede next row's writes).
    }
}

// ---------------------------------------------------------------- top-33 fallback (used only if ws too small)
__global__ __launch_bounds__(256) void topk_kernel(unsigned short* __restrict__ out) {
    const int row = blockIdx.x;
    unsigned short* rowp = out + (size_t)row * NN;
    const int t = threadIdx.x;
    const int lane = t & 63;
    const int wave = t >> 6;

    __shared__ unsigned short s_tmax[256];
    __shared__ unsigned int   s_cand[4][96];
    __shared__ int            s_cnum[4];
    __shared__ unsigned int   s_tau;
    __shared__ int            s_nsel;
    __shared__ int            s_selgi[40];

    uint4 d[8];
    const uint4* rp4 = (const uint4*)rowp;
#pragma unroll
    for (int j = 0; j < 8; ++j) d[j] = rp4[j * 256 + t];
    unsigned int tm = 0;
#pragma unroll
    for (int j = 0; j < 8; ++j) {
        const unsigned int* w = (const unsigned int*)&d[j];
#pragma unroll
        for (int q = 0; q < 4; ++q) {
            const unsigned int a = w[q] & 0xFFFFu, b = w[q] >> 16;
            const unsigned int m = a > b ? a : b;
            tm = m > tm ? m : tm;
        }
    }
    s_tmax[t] = (unsigned short)tm;
    __syncthreads();

    unsigned int k0 = s_tmax[lane],       k1 = s_tmax[lane + 64],
                 k2 = s_tmax[lane + 128], k3 = s_tmax[lane + 192];
    unsigned int taulb = 0;
#pragma unroll
    for (int b = 15; b >= 0; --b) {
        const unsigned int tc = taulb | (1u << b);
        const int c = (int)__popcll(__ballot(k0 >= tc)) + (int)__popcll(__ballot(k1 >= tc)) +
                      (int)__popcll(__ballot(k2 >= tc)) + (int)__popcll(__ballot(k3 >= tc));
        if (c >= KSEL) taulb = tc;
    }
    int cge = 0;
#pragma unroll
    for (int j = 0; j < 8; ++j) {
        const unsigned int* w = (const unsigned int*)&d[j];
#pragma unroll
        for (int q = 0; q < 4; ++q)
            cge += (int)((w[q] & 0xFFFFu) >= taulb) + (int)((w[q] >> 16) >= taulb);
    }
    int p = cge;
#pragma unroll
    for (int off = 1; off < 64; off <<= 1) {
        const int v = __shfl_up(p, off);
        if (lane >= off) p += v;
    }
    int slot = p - cge;
    if (cge) {
#pragma unroll
        for (int j = 0; j < 8; ++j) {
            const unsigned int* w = (const unsigned int*)&d[j];
#pragma unroll
            for (int q = 0; q < 4; ++q) {
#pragma unroll
                for (int h = 0; h < 2; ++h) {
                    const unsigned int k = h ? (w[q] >> 16) : (w[q] & 0xFFFFu);
                    if (k >= taulb) {
                        if (slot < 96)
                            s_cand[wave][slot] = (k << 16) | (unsigned int)((j << 11) + (t << 3) + q * 2 + h);
                        ++slot;
                    }
                }
            }
        }
    }
    if (lane == 63) s_cnum[wave] = (p < 96) ? p : 96;
    __syncthreads();

    if (wave == 0) {
        const int n0c = s_cnum[0], n1c = s_cnum[1], n2c = s_cnum[2], n3c = s_cnum[3];
        const int M = n0c + n1c + n2c + n3c;
        unsigned int e[6]; bool val[6];
#pragma unroll
        for (int s = 0; s < 6; ++s) {
            const int i = lane + 64 * s;
            val[s] = (i < M);
            unsigned int v = 0;
            if (val[s]) {
                int ii = i;
                if (ii < n0c) v = s_cand[0][ii];
                else { ii -= n0c;
                    if (ii < n1c) v = s_cand[1][ii];
                    else { ii -= n1c;
                        if (ii < n2c) v = s_cand[2][ii];
                        else v = s_cand[3][ii - n2c]; } }
            }
            e[s] = v;
        }
        unsigned int T = 0;
#pragma unroll
        for (int b = 15; b >= 0; --b) {
            const unsigned int tc = T | (1u << b);
            int c = 0;
#pragma unroll
            for (int s = 0; s < 6; ++s)
                c += (int)__popcll(__ballot(val[s] && (e[s] >> 16) >= tc));
            if (c >= KSEL) T = tc;
        }
        int cgt = 0;
#pragma unroll
        for (int s = 0; s < 6; ++s) cgt += (int)(val[s] && (e[s] >> 16) > T);
#pragma unroll
        for (int off = 1; off < 64; off <<= 1) cgt += __shfl_xor(cgt, off);
        int tneed = KSEL - cgt;
        if (tneed < 0) tneed = 0;
        if (tneed > 40) tneed = 40;
        bool taken[6] = {false, false, false, false, false, false};
        for (int k = 0; k < tneed; ++k) {
            int m = 0x7fffffff;
#pragma unroll
            for (int s = 0; s < 6; ++s)
                if (val[s] && !taken[s] && (e[s] >> 16) == T) {
                    const int g = (int)(e[s] & 0xFFFFu);
                    if (g < m) m = g;
                }
#pragma unroll
            for (int off = 1; off < 64; off <<= 1) {
                const int o = __shfl_xor(m, off);
                if (o < m) m = o;
            }
            if (m == 0x7fffffff) { if (lane == 0) s_selgi[k] = -1; continue; }
#pragma unroll
            for (int s = 0; s < 6; ++s)
                if (val[s] && !taken[s] && (e[s] >> 16) == T && (int)(e[s] & 0xFFFFu) == m) {
                    taken[s] = true;
                    s_selgi[k] = m;
                }
        }
        if (lane == 0) { s_tau = T; s_nsel = tneed; }
    }
    __syncthreads();

    const unsigned int T = s_tau;
    const int nsel = s_nsel;
    unsigned long long cons = 0ull;
    for (int k = 0; k < nsel; ++k) {
        const int g = s_selgi[k];
        if (g >= 0 && ((g >> 3) & 255) == t) cons |= 1ull << (((g >> 11) << 3) | (g & 7));
    }
    uint4* wp4 = (uint4*)rowp;
#pragma unroll
    for (int j = 0; j < 8; ++j) {
        const unsigned int* w = (const unsigned int*)&d[j];
        uint4 o;
        unsigned int* ow = (unsigned int*)&o;
#pragma unroll
        for (int q = 0; q < 4; ++q) {
            const unsigned int klo = w[q] & 0xFFFFu, khi = w[q] >> 16;
            const int ord = j * 8 + q * 2;
            const bool sl = (klo > T) || ((cons >> ord) & 1ull);
            const bool sh = (khi > T) || ((cons >> (ord + 1)) & 1ull);
            const unsigned int lo = sl ? keyd2_to_out(klo) : 0xFBFFu;
            const unsigned int hi = sh ? keyd2_to_out(khi) : 0xFBFFu;
            ow[q] = lo | (hi << 16);
        }
        wp4[j * 256 + t] = o;
    }
}

// ---------------------------------------------------------------- launch
extern "C" void kernel_launch(void* const* d_in, const int* in_sizes, int n_in,
                              void* d_out, int out_size, void* d_ws, size_t ws_size,
                              hipStream_t stream) {
    const unsigned short* x  = (const unsigned short*)d_in[0];   // [4096 x 256] f16
    const unsigned short* xn = (const unsigned short*)d_in[1];   // [16384 x 256] f16
    unsigned short* out = (unsigned short*)d_out;                // [4096 x 16384] f16
    float* ws = (float*)d_ws;
    unsigned short* tmax = (unsigned short*)((char*)d_ws + WS_NORMS);

    if (ws_size >= WS_FULL) {
        norms_kernel<<<(Q + NN) / 64, 256, 0, stream>>>(x, xn, ws);
        gemm_sim_kernel<true, true><<<dim3(NN / 128, Q / 128), 256, 0, stream>>>(x, xn, ws, tmax, out);
        rowsel_kernel<<<Q / 8, 256, 0, stream>>>(out, tmax);
    } else if (ws_size >= WS_NORMS) {
        norms_kernel<<<(Q + NN) / 64, 256, 0, stream>>>(x, xn, ws);
        gemm_sim_kernel<true, false><<<dim3(NN / 128, Q / 128), 256, 0, stream>>>(x, xn, ws, nullptr, out);
        topk_kernel<<<Q, 256, 0, stream>>>(out);
    } else {
        gemm_sim_kernel<false, false><<<dim3(NN / 128, Q / 128), 256, 0, stream>>>(x, xn, nullptr, nullptr, out);
        topk_kernel<<<Q, 256, 0, stream>>>(out);
    }
}

// Round 10
// 340.650 us; speedup vs baseline: 1.0969x; 1.0969x over previous
//
#include <hip/hip_runtime.h>
#include <hip/hip_fp16.h>
#include <math.h>

#define Q    4096
#define NN   16384
#define DD   256
#define KSEL 33
#define CANDW 256  // per-ROW candidate cap (rowsel)
#define CAND 96    // per-wave cap (legacy fallback kernels)
#define OSTR 264   // epilogue LDS row stride bytes: 256 B data + 8 B pad
#define TM_BYTES (128 * Q * 2)                 // tilemax[tileN][row] u16 keys
#define WS_NORMS ((size_t)(Q + NN) * 4)
#define WS_FULL  (WS_NORMS + TM_BYTES)

typedef __attribute__((ext_vector_type(8))) _Float16 half8;
typedef __attribute__((ext_vector_type(4))) float    floatx4;

__device__ __forceinline__ float h2f(unsigned short u) {
    union { unsigned short s; _Float16 h; } c; c.s = u;
    return (float)c.h;
}
__device__ __forceinline__ unsigned short f2h_finite(float v) {
    v = fminf(fmaxf(v, -65504.0f), 65504.0f);
    union { _Float16 h; unsigned short s; } c; c.h = (_Float16)v;
    unsigned short u = c.s;
    if ((u & 0x7C00u) == 0x7C00u) u = (u & 0x8000u) ? 0xFBFFu : 0x7BFFu;
    return u;
}
__device__ __forceinline__ unsigned int patch16(unsigned int u) {
    if ((u & 0x7C00u) == 0x7C00u) u = (u & 0x8000u) ? 0xFBFFu : 0x7BFFu;
    return u;
}
// keys: u16 = f16bits(-d2) ^ 0xFFFF (monotone for values <= 0, involutive)
__device__ __forceinline__ unsigned short keyd2_to_out(unsigned int k) {
    const float nd2 = h2f((unsigned short)patch16(k ^ 0xFFFFu));
    return f2h_finite(-sqrtf(fmaxf(-nd2, 0.0f)));
}
__device__ __forceinline__ void gload_lds16(const unsigned short* g, char* l) {
    __builtin_amdgcn_global_load_lds(
        (const __attribute__((address_space(1))) void*)g,
        (__attribute__((address_space(3))) void*)l, 16, 0, 0);
}

// ---------------------------------------------------------------- row norms -> ws
__global__ __launch_bounds__(256) void norms_kernel(const unsigned short* __restrict__ x,
                                                    const unsigned short* __restrict__ xn,
                                                    float* __restrict__ ws) {
    const int t = threadIdx.x;
    const int g = blockIdx.x * 64 + (t >> 2);
    const int sub = t & 3;
    const unsigned short* src = (g < Q) ? (x + (size_t)g * DD)
                                        : (xn + (size_t)(g - Q) * DD);
    float s = 0.f;
#pragma unroll
    for (int it = 0; it < 8; ++it) {
        const uint4 v = *(const uint4*)(src + (it * 4 + sub) * 8);
        const unsigned int* w = (const unsigned int*)&v;
#pragma unroll
        for (int q = 0; q < 4; ++q) {
            const float a = h2f(w[q] & 0xFFFF), b = h2f(w[q] >> 16);
            s = fmaf(a, a, s); s = fmaf(b, b, s);
        }
    }
    s += __shfl_xor(s, 1);
    s += __shfl_xor(s, 2);
    if (sub == 0) ws[g] = s;
}

// ---------------------------------------------------------------- sim GEMM v2: 128x256 tile, 8 waves
// R10: halve block count (2048 vs 4096) -> half the pipeline-warmup events
// (dominant per-block cost at K=256), 25% less L2 panel traffic, 3 blocks/CU
// (48 KB LDS staging union) = 24 waves/CU. Two-phase epilogue (left/right
// 128-col halves through one 33.8 KB buffer) dodges the 64 KB static-LDS cap.
// Keys/tilemax identical to validated R8 path.
__global__ __launch_bounds__(512) void gemm256_kernel(const unsigned short* __restrict__ A,
                                                      const unsigned short* __restrict__ B,
                                                      const float* __restrict__ ws,
                                                      unsigned short* __restrict__ tmax,
                                                      unsigned short* __restrict__ out) {
    __shared__ char  lds[49152];     // staging: A 16 KB + B 32 KB; epilogue reuses [0,33792)
    __shared__ float s_x2[128];
    __shared__ float s_y2[256];
    char* ldsA = lds;                // [kk2][128 rows][64 B]
    char* ldsB = lds + 16384;        // [kk2][256 rows][64 B]

    const int t    = threadIdx.x;    // 0..511
    // XCD swizzle: 2048 blocks, xcd owns 8 n-supers (256-wide) x all 32 m-tiles
    const int bid  = blockIdx.x;
    const int xcd  = bid & 7;
    const int qb   = bid >> 3;                    // 0..255
    const int n0   = ((xcd << 3) | (qb & 7)) << 8;   // n-super * 256
    const int m0   = (qb >> 3) << 7;                 // m-tile * 128
    const int wave = t >> 6;         // 0..7
    const int lane = t & 63;
    const int wm   = (wave & 1) << 6;        // 0,64
    const int wn   = (wave >> 1) << 6;       // 0,64,128,192
    const int l15  = lane & 15;
    const int quad = lane >> 4;
    const int r0   = t >> 2;         // 0..127
    const int qq   = t & 3;

    if (t < 128) s_x2[t] = ws[m0 + t];
    else if (t < 384) s_y2[t - 128] = ws[Q + n0 + (t - 128)];

    floatx4 acc[4][4];
#pragma unroll
    for (int i = 0; i < 4; ++i)
#pragma unroll
        for (int j = 0; j < 4; ++j) {
            acc[i][j][0] = 0.f; acc[i][j][1] = 0.f; acc[i][j][2] = 0.f; acc[i][j][3] = 0.f;
        }

    // prologue: issue tile 0 (A: 2 segs, B: 4 segs; LDS dest = seg*8192 + t*16)
#pragma unroll
    for (int j = 0; j < 2; ++j)
        gload_lds16(A + (size_t)(m0 + r0) * DD + j * 32 + qq * 8, ldsA + j * 8192 + t * 16);
#pragma unroll
    for (int j = 0; j < 4; ++j)
        gload_lds16(B + (size_t)(n0 + ((j & 1) << 7) + r0) * DD + ((j >> 1) << 5) + qq * 8,
                    ldsB + j * 8192 + t * 16);

#pragma unroll
    for (int kt = 0; kt < 4; ++kt) {
        __syncthreads();             // b1: tile kt loads landed (vmcnt drained)
        half8 af[2][4], bg[2][4];
#pragma unroll
        for (int kk = 0; kk < 2; ++kk)
#pragma unroll
            for (int s = 0; s < 4; ++s) {
                af[kk][s] = *(const half8*)(ldsA + (kk << 13) + (wm + s * 16 + l15) * 64 + quad * 16);
                bg[kk][s] = *(const half8*)(ldsB + (kk << 14) + (wn + s * 16 + l15) * 64 + quad * 16);
            }
        __syncthreads();             // b2: all waves' frags in regs
        if (kt < 3) {
            const int kn = (kt + 1) * 64;
#pragma unroll
            for (int j = 0; j < 2; ++j)
                gload_lds16(A + (size_t)(m0 + r0) * DD + kn + j * 32 + qq * 8, ldsA + j * 8192 + t * 16);
#pragma unroll
            for (int j = 0; j < 4; ++j)
                gload_lds16(B + (size_t)(n0 + ((j & 1) << 7) + r0) * DD + kn + ((j >> 1) << 5) + qq * 8,
                            ldsB + j * 8192 + t * 16);
        }
#pragma unroll
        for (int kk = 0; kk < 2; ++kk)
#pragma unroll
            for (int si = 0; si < 4; ++si)
#pragma unroll
                for (int sj = 0; sj < 4; ++sj)
                    acc[si][sj] = __builtin_amdgcn_mfma_f32_16x16x32_f16(af[kk][si], bg[kk][sj], acc[si][sj], 0, 0, 0);
    }

    // ---- two-phase epilogue + store (left cols 0..127 by waves 0-3, right by 4-7)
#pragma unroll
    for (int ph = 0; ph < 2; ++ph) {
        const bool mine = (wave >> 2) == ph;     // waves 0-3 phase 0, 4-7 phase 1
        if (mine) {
            const int cb0 = wn - ph * 128;       // local col base 0..112
            float ny[4];
#pragma unroll
            for (int sj = 0; sj < 4; ++sj) ny[sj] = -s_y2[wn + sj * 16 + l15];
#pragma unroll
            for (int si = 0; si < 4; ++si) {
#pragma unroll
                for (int r = 0; r < 4; ++r) {
                    const int lrow = wm + si * 16 + quad * 4 + r;
                    const float nx = -s_x2[lrow];
#pragma unroll
                    for (int sj = 0; sj < 4; ++sj) {
                        const float nd2 = fminf(fmaf(2.0f, acc[si][sj][r], nx + ny[sj]), 0.0f);
                        union { _Float16 h; unsigned short s; } c; c.h = (_Float16)nd2;
                        *(unsigned short*)(lds + lrow * OSTR + (cb0 + sj * 16 + l15) * 2) =
                            (unsigned short)(c.s ^ 0xFFFFu);
                    }
                }
            }
        }
        __syncthreads();             // keys of this half ready
        // store pass: 128 rows x 16 chunks / 512 threads = 4 iters; fused tilemax
#pragma unroll
        for (int p = 0; p < 4; ++p) {
            const int idx = p * 512 + t;
            const int r = idx >> 4, c = idx & 15;
            const uint4 v = *(const uint4*)(lds + r * OSTR + c * 16);
            *(uint4*)(out + (size_t)(m0 + r) * NN + n0 + ph * 128 + c * 8) = v;
            const unsigned int* w = (const unsigned int*)&v;
            unsigned int mk = 0;
#pragma unroll
            for (int q = 0; q < 4; ++q) {
                const unsigned int a = w[q] & 0xFFFFu, b = w[q] >> 16;
                const unsigned int m = a > b ? a : b;
                mk = m > mk ? m : mk;
            }
#pragma unroll
            for (int off = 1; off < 16; off <<= 1) {
                const unsigned int o = (unsigned int)__shfl_xor((int)mk, off);
                mk = o > mk ? o : mk;
            }
            if (c == 0) tmax[(size_t)((n0 >> 7) + ph) * Q + m0 + r] = (unsigned short)mk;
        }
        if (ph == 0) __syncthreads();            // pass-A reads done before right-half writes
    }
}

// ---------------------------------------------------------------- sim GEMM (legacy 128x128, fallback paths only)
template <bool WS, bool TM>
__global__ __launch_bounds__(256) void gemm_sim_kernel(const unsigned short* __restrict__ A,
                                                       const unsigned short* __restrict__ B,
                                                       const float* __restrict__ ws,
                                                       unsigned short* __restrict__ tmax,
                                                       unsigned short* __restrict__ out) {
    __shared__ char  lds[128 * OSTR];
    __shared__ float s_x2[128];
    __shared__ float s_y2[128];
    char* ldsA = lds;
    char* ldsB = lds + 16384;

    const int t    = threadIdx.x;
    const int bid  = blockIdx.x + blockIdx.y * (NN / 128);
    const int xcd  = bid & 7;
    const int qb   = bid >> 3;
    const int n0   = ((xcd << 4) | (qb & 15)) * 128;
    const int m0   = (qb >> 4) * 128;
    const int wave = t >> 6;
    const int lane = t & 63;
    const int wm   = (wave & 1) << 6;
    const int wn   = (wave >> 1) << 6;
    const int l15  = lane & 15;
    const int quad = lane >> 4;
    const int r0   = t >> 2;
    const int qq   = t & 3;

    if (WS) {
        if (t < 128) s_x2[t] = ws[m0 + t];
        else         s_y2[t - 128] = ws[Q + n0 + (t - 128)];
    }

    floatx4 acc[4][4];
#pragma unroll
    for (int i = 0; i < 4; ++i)
#pragma unroll
        for (int j = 0; j < 4; ++j) {
            acc[i][j][0] = 0.f; acc[i][j][1] = 0.f; acc[i][j][2] = 0.f; acc[i][j][3] = 0.f;
        }
    float pa[2] = {0.f, 0.f}, pb[2] = {0.f, 0.f};

    if (WS) {
#pragma unroll
        for (int j = 0; j < 4; ++j) {
            const int row = ((j & 1) << 6) + r0;
            const int kd  = ((j >> 1) << 5) + (qq << 3);
            gload_lds16(A + (size_t)(m0 + row) * DD + kd, ldsA + j * 4096 + t * 16);
            gload_lds16(B + (size_t)(n0 + row) * DD + kd, ldsB + j * 4096 + t * 16);
        }
#pragma unroll
        for (int kt = 0; kt < 4; ++kt) {
            __syncthreads();
            half8 af[2][4], bg[2][4];
#pragma unroll
            for (int kk = 0; kk < 2; ++kk)
#pragma unroll
                for (int s = 0; s < 4; ++s) {
                    af[kk][s] = *(const half8*)(ldsA + (kk << 13) + (wm + s * 16 + l15) * 64 + quad * 16);
                    bg[kk][s] = *(const half8*)(ldsB + (kk << 13) + (wn + s * 16 + l15) * 64 + quad * 16);
                }
            __syncthreads();
            if (kt < 3) {
                const int kn = (kt + 1) * 64;
#pragma unroll
                for (int j = 0; j < 4; ++j) {
                    const int row = ((j & 1) << 6) + r0;
                    const int kd  = kn + ((j >> 1) << 5) + (qq << 3);
                    gload_lds16(A + (size_t)(m0 + row) * DD + kd, ldsA + j * 4096 + t * 16);
                    gload_lds16(B + (size_t)(n0 + row) * DD + kd, ldsB + j * 4096 + t * 16);
                }
            }
#pragma unroll
            for (int kk = 0; kk < 2; ++kk)
#pragma unroll
                for (int si = 0; si < 4; ++si)
#pragma unroll
                    for (int sj = 0; sj < 4; ++sj)
                        acc[si][sj] = __builtin_amdgcn_mfma_f32_16x16x32_f16(af[kk][si], bg[kk][sj], acc[si][sj], 0, 0, 0);
        }
    } else {
        for (int k0 = 0; k0 < DD; k0 += 64) {
            float4 ar[4], br[4];
#pragma unroll
            for (int j = 0; j < 4; ++j) {
                const int r  = r0 + ((j & 1) << 6);
                const int kd = k0 + ((j >> 1) << 5);
                ar[j] = *(const float4*)(A + (size_t)(m0 + r) * DD + kd + qq * 8);
                br[j] = *(const float4*)(B + (size_t)(n0 + r) * DD + kd + qq * 8);
                const unsigned short* ua = (const unsigned short*)&ar[j];
                const unsigned short* ub = (const unsigned short*)&br[j];
#pragma unroll
                for (int e = 0; e < 8; ++e) {
                    const float fa = h2f(ua[e]); pa[j & 1] = fmaf(fa, fa, pa[j & 1]);
                    const float fb = h2f(ub[e]); pb[j & 1] = fmaf(fb, fb, pb[j & 1]);
                }
            }
            __syncthreads();
#pragma unroll
            for (int j = 0; j < 4; ++j) {
                const int r = r0 + ((j & 1) << 6);
                *(float4*)(ldsA + ((j >> 1) << 13) + r * 64 + qq * 16) = ar[j];
                *(float4*)(ldsB + ((j >> 1) << 13) + r * 64 + qq * 16) = br[j];
            }
            __syncthreads();
#pragma unroll
            for (int kk = 0; kk < 2; ++kk) {
                half8 af[4], bg[4];
#pragma unroll
                for (int s = 0; s < 4; ++s) {
                    af[s] = *(const half8*)(ldsA + (kk << 13) + (wm + s * 16 + l15) * 64 + quad * 16);
                    bg[s] = *(const half8*)(ldsB + (kk << 13) + (wn + s * 16 + l15) * 64 + quad * 16);
                }
#pragma unroll
                for (int si = 0; si < 4; ++si)
#pragma unroll
                    for (int sj = 0; sj < 4; ++sj)
                        acc[si][sj] = __builtin_amdgcn_mfma_f32_16x16x32_f16(af[si], bg[sj], acc[si][sj], 0, 0, 0);
            }
            __syncthreads();
        }
#pragma unroll
        for (int j = 0; j < 2; ++j) {
            pa[j] += __shfl_xor(pa[j], 1); pa[j] += __shfl_xor(pa[j], 2);
            pb[j] += __shfl_xor(pb[j], 1); pb[j] += __shfl_xor(pb[j], 2);
        }
        if (qq == 0) {
            s_x2[r0] = pa[0]; s_x2[64 + r0] = pa[1];
            s_y2[r0] = pb[0]; s_y2[64 + r0] = pb[1];
        }
        __syncthreads();
    }

    {
        float ny[4];
#pragma unroll
        for (int sj = 0; sj < 4; ++sj) ny[sj] = -s_y2[wn + sj * 16 + l15];
#pragma unroll
        for (int si = 0; si < 4; ++si) {
#pragma unroll
            for (int r = 0; r < 4; ++r) {
                const int lrow = wm + si * 16 + quad * 4 + r;
                const float nx = -s_x2[lrow];
#pragma unroll
                for (int sj = 0; sj < 4; ++sj) {
                    const float nd2 = fminf(fmaf(2.0f, acc[si][sj][r], nx + ny[sj]), 0.0f);
                    union { _Float16 h; unsigned short s; } c; c.h = (_Float16)nd2;
                    *(unsigned short*)(lds + lrow * OSTR + (wn + sj * 16 + l15) * 2) =
                        (unsigned short)(c.s ^ 0xFFFFu);
                }
            }
        }
    }
    __syncthreads();

#pragma unroll
    for (int p = 0; p < 8; ++p) {
        const int idx = p * 256 + t;
        const int r = idx >> 4, c = idx & 15;
        const uint4 v = *(const uint4*)(lds + r * OSTR + c * 16);
        *(uint4*)(out + (size_t)(m0 + r) * NN + n0 + c * 8) = v;
        if (TM) {
            const unsigned int* w = (const unsigned int*)&v;
            unsigned int mk = 0;
#pragma unroll
            for (int q = 0; q < 4; ++q) {
                const unsigned int a = w[q] & 0xFFFFu, b = w[q] >> 16;
                const unsigned int m = a > b ? a : b;
                mk = m > mk ? m : mk;
            }
#pragma unroll
            for (int off = 1; off < 16; off <<= 1) {
                const unsigned int o = (unsigned int)__shfl_xor((int)mk, off);
                mk = o > mk ? o : mk;
            }
            if (c == 0) tmax[(size_t)(n0 >> 7) * Q + m0 + r] = (unsigned short)mk;
        }
    }
}

// ---------------------------------------------------------------- row select v6 (R8): wave-per-row, zero barriers
__global__ __launch_bounds__(256) void rowsel_kernel(unsigned short* __restrict__ out,
                                                     const unsigned short* __restrict__ tmax) {
    const int t = threadIdx.x;
    const int lane = t & 63;
    const int wave = t >> 6;
    const int row = blockIdx.x * 4 + wave;
    unsigned short* rowp = out + (size_t)row * NN;

    __shared__ unsigned short s_tm[4][128];
    __shared__ unsigned int   s_cand[4][CANDW];   // (key<<16) | col

    const unsigned int ka = tmax[(size_t)(2 * lane) * Q + row];
    const unsigned int kb = tmax[(size_t)(2 * lane + 1) * Q + row];
    s_tm[wave][2 * lane]     = (unsigned short)ka;
    s_tm[wave][2 * lane + 1] = (unsigned short)kb;

    unsigned int taulb = 0;
#pragma unroll
    for (int b = 15; b >= 0; --b) {
        const unsigned int tc = taulb | (1u << b);
        const int c = (int)__popcll(__ballot(ka >= tc)) + (int)__popcll(__ballot(kb >= tc));
        if (c >= KSEL) taulb = tc;           // wave-uniform
    }
    asm volatile("s_waitcnt lgkmcnt(0)" ::: "memory");   // s_tm visible (same wave)

    int wbase = 0;
#pragma unroll
    for (int pass = 0; pass < 4; ++pass) {
        const int half  = pass * 64 + lane;
        const int cbase = half * 64;
        const bool act  = s_tm[wave][half >> 1] >= taulb;
        if (__ballot(act)) {
            uint4 d[8];
            int cge = 0;
            if (act) {
                const uint4* tp = (const uint4*)(rowp + cbase);
#pragma unroll
                for (int j = 0; j < 8; ++j) d[j] = tp[j];
#pragma unroll
                for (int j = 0; j < 8; ++j) {
                    const unsigned int* w = (const unsigned int*)&d[j];
#pragma unroll
                    for (int q = 0; q < 4; ++q)
                        cge += (int)((w[q] & 0xFFFFu) >= taulb) + (int)((w[q] >> 16) >= taulb);
                }
            }
            int p = cge;
#pragma unroll
            for (int off = 1; off < 64; off <<= 1) {
                const int v = __shfl_up(p, off);
                if (lane >= off) p += v;
            }
            int slot = wbase + p - cge;
            if (cge) {
#pragma unroll
                for (int j = 0; j < 8; ++j) {
                    const unsigned int* w = (const unsigned int*)&d[j];
#pragma unroll
                    for (int q = 0; q < 4; ++q) {
#pragma unroll
                        for (int hh = 0; hh < 2; ++hh) {
                            const unsigned int k = hh ? (w[q] >> 16) : (w[q] & 0xFFFFu);
                            if (k >= taulb) {
                                if (slot < CANDW)
                                    s_cand[wave][slot] = (k << 16) | (unsigned int)(cbase + j * 8 + q * 2 + hh);
                                ++slot;
                            }
                        }
                    }
                }
            }
            wbase += __shfl(p, 63);
            if (wbase > CANDW) wbase = CANDW;
        }
    }
    const int M = wbase;

    asm volatile("s_waitcnt lgkmcnt(0)" ::: "memory");
    unsigned int e[4]; bool val[4];
#pragma unroll
    for (int s = 0; s < 4; ++s) {
        const int i = lane + 64 * s;
        val[s] = (i < M);
        e[s] = val[s] ? s_cand[wave][i] : 0u;
    }

    const uint4 fv = {0xFBFFFBFFu, 0xFBFFFBFFu, 0xFBFFFBFFu, 0xFBFFFBFFu};
    uint4* wp4 = (uint4*)rowp;
#pragma unroll
    for (int j = 0; j < 32; ++j) wp4[j * 64 + lane] = fv;

    unsigned int T = 0;
#pragma unroll
    for (int b = 15; b >= 0; --b) {
        const unsigned int tc = T | (1u << b);
        int c = 0;
#pragma unroll
        for (int s = 0; s < 4; ++s)
            c += (int)__popcll(__ballot(val[s] && (e[s] >> 16) >= tc));
        if (c >= KSEL) T = tc;
    }
    int cgt = 0;
    bool sel[4];
#pragma unroll
    for (int s = 0; s < 4; ++s) {
        sel[s] = val[s] && (e[s] >> 16) > T;
        cgt += (int)__popcll(__ballot(sel[s]));
    }
    int tneed = KSEL - cgt;
    if (tneed < 0) tneed = 0;

    asm volatile("s_waitcnt vmcnt(0)" ::: "memory");     // fill completed

#pragma unroll
    for (int s = 0; s < 4; ++s)
        if (sel[s]) rowp[e[s] & 0xFFFFu] = keyd2_to_out(e[s] >> 16);

    const unsigned short tval = keyd2_to_out(T);
    bool taken[4] = {false, false, false, false};
    for (int k = 0; k < tneed; ++k) {
        int m = 0x7fffffff;
#pragma unroll
        for (int s = 0; s < 4; ++s)
            if (val[s] && !taken[s] && (e[s] >> 16) == T) {
                const int g = (int)(e[s] & 0xFFFFu);
                if (g < m) m = g;
            }
#pragma unroll
        for (int off = 1; off < 64; off <<= 1) {
            const int o = __shfl_xor(m, off);
            if (o < m) m = o;
        }
        if (m == 0x7fffffff) break;
#pragma unroll
        for (int s = 0; s < 4; ++s)
            if (val[s] && !taken[s] && (e[s] >> 16) == T && (int)(e[s] & 0xFFFFu) == m) {
                taken[s] = true;
                rowp[m] = tval;
            }
    }
}

// ---------------------------------------------------------------- top-33 fallback (used only if ws too small)
__global__ __launch_bounds__(256) void topk_kernel(unsigned short* __restrict__ out) {
    const int row = blockIdx.x;
    unsigned short* rowp = out + (size_t)row * NN;
    const int t = threadIdx.x;
    const int lane = t & 63;
    const int wave = t >> 6;

    __shared__ unsigned short s_tmax[256];
    __shared__ unsigned int   s_cand[4][CAND];
    __shared__ int            s_cnum[4];
    __shared__ unsigned int   s_tau;
    __shared__ int            s_nsel;
    __shared__ int            s_selgi[40];

    uint4 d[8];
    const uint4* rp4 = (const uint4*)rowp;
#pragma unroll
    for (int j = 0; j < 8; ++j) d[j] = rp4[j * 256 + t];
    unsigned int tm = 0;
#pragma unroll
    for (int j = 0; j < 8; ++j) {
        const unsigned int* w = (const unsigned int*)&d[j];
#pragma unroll
        for (int q = 0; q < 4; ++q) {
            const unsigned int a = w[q] & 0xFFFFu, b = w[q] >> 16;
            const unsigned int m = a > b ? a : b;
            tm = m > tm ? m : tm;
        }
    }
    s_tmax[t] = (unsigned short)tm;
    __syncthreads();

    unsigned int k0 = s_tmax[lane],       k1 = s_tmax[lane + 64],
                 k2 = s_tmax[lane + 128], k3 = s_tmax[lane + 192];
    unsigned int taulb = 0;
#pragma unroll
    for (int b = 15; b >= 0; --b) {
        const unsigned int tc = taulb | (1u << b);
        const int c = (int)__popcll(__ballot(k0 >= tc)) + (int)__popcll(__ballot(k1 >= tc)) +
                      (int)__popcll(__ballot(k2 >= tc)) + (int)__popcll(__ballot(k3 >= tc));
        if (c >= KSEL) taulb = tc;
    }
    int cge = 0;
#pragma unroll
    for (int j = 0; j < 8; ++j) {
        const unsigned int* w = (const unsigned int*)&d[j];
#pragma unroll
        for (int q = 0; q < 4; ++q)
            cge += (int)((w[q] & 0xFFFFu) >= taulb) + (int)((w[q] >> 16) >= taulb);
    }
    int p = cge;
#pragma unroll
    for (int off = 1; off < 64; off <<= 1) {
        const int v = __shfl_up(p, off);
        if (lane >= off) p += v;
    }
    int slot = p - cge;
    if (cge) {
#pragma unroll
        for (int j = 0; j < 8; ++j) {
            const unsigned int* w = (const unsigned int*)&d[j];
#pragma unroll
            for (int q = 0; q < 4; ++q) {
#pragma unroll
                for (int h = 0; h < 2; ++h) {
                    const unsigned int k = h ? (w[q] >> 16) : (w[q] & 0xFFFFu);
                    if (k >= taulb) {
                        if (slot < CAND)
                            s_cand[wave][slot] = (k << 16) | (unsigned int)((j << 11) + (t << 3) + q * 2 + h);
                        ++slot;
                    }
                }
            }
        }
    }
    if (lane == 63) s_cnum[wave] = (p < CAND) ? p : CAND;
    __syncthreads();

    if (wave == 0) {
        const int n0c = s_cnum[0], n1c = s_cnum[1], n2c = s_cnum[2], n3c = s_cnum[3];
        const int M = n0c + n1c + n2c + n3c;
        unsigned int e[6]; bool val[6];
#pragma unroll
        for (int s = 0; s < 6; ++s) {
            const int i = lane + 64 * s;
            val[s] = (i < M);
            unsigned int v = 0;
            if (val[s]) {
                int ii = i;
                if (ii < n0c) v = s_cand[0][ii];
                else { ii -= n0c;
                    if (ii < n1c) v = s_cand[1][ii];
                    else { ii -= n1c;
                        if (ii < n2c) v = s_cand[2][ii];
                        else v = s_cand[3][ii - n2c]; } }
            }
            e[s] = v;
        }
        unsigned int T = 0;
#pragma unroll
        for (int b = 15; b >= 0; --b) {
            const unsigned int tc = T | (1u << b);
            int c = 0;
#pragma unroll
            for (int s = 0; s < 6; ++s)
                c += (int)__popcll(__ballot(val[s] && (e[s] >> 16) >= tc));
            if (c >= KSEL) T = tc;
        }
        int cgt = 0;
#pragma unroll
        for (int s = 0; s < 6; ++s) cgt += (int)(val[s] && (e[s] >> 16) > T);
#pragma unroll
        for (int off = 1; off < 64; off <<= 1) cgt += __shfl_xor(cgt, off);
        int tneed = KSEL - cgt;
        if (tneed < 0) tneed = 0;
        if (tneed > 40) tneed = 40;
        bool taken[6] = {false, false, false, false, false, false};
        for (int k = 0; k < tneed; ++k) {
            int m = 0x7fffffff;
#pragma unroll
            for (int s = 0; s < 6; ++s)
                if (val[s] && !taken[s] && (e[s] >> 16) == T) {
                    const int g = (int)(e[s] & 0xFFFFu);
                    if (g < m) m = g;
                }
#pragma unroll
            for (int off = 1; off < 64; off <<= 1) {
                const int o = __shfl_xor(m, off);
                if (o < m) m = o;
            }
            if (m == 0x7fffffff) { if (lane == 0) s_selgi[k] = -1; continue; }
#pragma unroll
            for (int s = 0; s < 6; ++s)
                if (val[s] && !taken[s] && (e[s] >> 16) == T && (int)(e[s] & 0xFFFFu) == m) {
                    taken[s] = true;
                    s_selgi[k] = m;
                }
        }
        if (lane == 0) { s_tau = T; s_nsel = tneed; }
    }
    __syncthreads();

    const unsigned int T = s_tau;
    const int nsel = s_nsel;
    unsigned long long cons = 0ull;
    for (int k = 0; k < nsel; ++k) {
        const int g = s_selgi[k];
        if (g >= 0 && ((g >> 3) & 255) == t) cons |= 1ull << (((g >> 11) << 3) | (g & 7));
    }
    uint4* wp4 = (uint4*)rowp;
#pragma unroll
    for (int j = 0; j < 8; ++j) {
        const unsigned int* w = (const unsigned int*)&d[j];
        uint4 o;
        unsigned int* ow = (unsigned int*)&o;
#pragma unroll
        for (int q = 0; q < 4; ++q) {
            const unsigned int klo = w[q] & 0xFFFFu, khi = w[q] >> 16;
            const int ord = j * 8 + q * 2;
            const bool sl = (klo > T) || ((cons >> ord) & 1ull);
            const bool sh = (khi > T) || ((cons >> (ord + 1)) & 1ull);
            const unsigned int lo = sl ? keyd2_to_out(klo) : 0xFBFFu;
            const unsigned int hi = sh ? keyd2_to_out(khi) : 0xFBFFu;
            ow[q] = lo | (hi << 16);
        }
        wp4[j * 256 + t] = o;
    }
}

// ---------------------------------------------------------------- launch
extern "C" void kernel_launch(void* const* d_in, const int* in_sizes, int n_in,
                              void* d_out, int out_size, void* d_ws, size_t ws_size,
                              hipStream_t stream) {
    const unsigned short* x  = (const unsigned short*)d_in[0];   // [4096 x 256] f16
    const unsigned short* xn = (const unsigned short*)d_in[1];   // [16384 x 256] f16
    unsigned short* out = (unsigned short*)d_out;                // [4096 x 16384] f16
    float* ws = (float*)d_ws;
    unsigned short* tmax = (unsigned short*)((char*)d_ws + WS_NORMS);

    if (ws_size >= WS_FULL) {
        norms_kernel<<<(Q + NN) / 64, 256, 0, stream>>>(x, xn, ws);
        gemm256_kernel<<<2048, 512, 0, stream>>>(x, xn, ws, tmax, out);
        rowsel_kernel<<<Q / 4, 256, 0, stream>>>(out, tmax);
    } else if (ws_size >= WS_NORMS) {
        norms_kernel<<<(Q + NN) / 64, 256, 0, stream>>>(x, xn, ws);
        gemm_sim_kernel<true, false><<<dim3(NN / 128, Q / 128), 256, 0, stream>>>(x, xn, ws, nullptr, out);
        topk_kernel<<<Q, 256, 0, stream>>>(out);
    } else {
        gemm_sim_kernel<false, false><<<dim3(NN / 128, Q / 128), 256, 0, stream>>>(x, xn, nullptr, nullptr, out);
        topk_kernel<<<Q, 256, 0, stream>>>(out);
    }
}